// Round 6
// baseline (597.657 us; speedup 1.0000x reference)
//
#include <hip/hip_runtime.h>

#define HW 16384
#define EPSF 1e-5f

typedef __attribute__((ext_vector_type(8))) short s8v;     // 8 bf16 (4 VGPRs)
typedef __attribute__((ext_vector_type(16))) float f16v;   // 32x32 accum

__device__ __forceinline__ ushort f2b(float f) {           // fp32 -> bf16 RNE
    union { float f; unsigned u; } v; v.f = f;
    return (ushort)((v.u + 0x7FFFu + ((v.u >> 16) & 1u)) >> 16);
}
__device__ __forceinline__ float b2f(ushort h) {
    union { unsigned u; float f; } v; v.u = ((unsigned)h) << 16; return v.f;
}

// out-region map (ushort offsets into d_out):
//   A-half of out-batch k (ch 0:64):   k*4194304 .. +2097152 ushorts (4 MB)
//   B-half of out-batch k (ch 64:128): k*4194304 + 2097152 (4 MB)
// c1[local j] (8 MB) -> A-halves of out-batches 2j, 2j+1 (row piece = y>>6)
// c2[b] bf16 NHWC    -> B-half of batch b
// edge[b] bf16 NHWC  -> A-half of batch b (after c1 dead)

// ---------------- BN folding
__global__ void bn_prep(const float* __restrict__ b1, const float* __restrict__ g1,
                        const float* __restrict__ be1, const float* __restrict__ m1,
                        const float* __restrict__ v1,
                        const float* __restrict__ b2, const float* __restrict__ g2,
                        const float* __restrict__ be2, const float* __restrict__ m2,
                        const float* __restrict__ v2,
                        const float* __restrict__ b3, const float* __restrict__ g3,
                        const float* __restrict__ be3, const float* __restrict__ m3,
                        const float* __restrict__ v3,
                        float* __restrict__ ws) {
    int t = threadIdx.x;
    if (t < 256) { float a = g1[t] * rsqrtf(v1[t] + EPSF); ws[t] = a;       ws[256 + t] = (b1[t] - m1[t]) * a + be1[t]; }
    if (t < 128) { float a = g2[t] * rsqrtf(v2[t] + EPSF); ws[512 + t] = a; ws[640 + t] = (b2[t] - m2[t]) * a + be2[t]; }
    if (t < 64)  { float a = g3[t] * rsqrtf(v3[t] + EPSF); ws[768 + t] = a; ws[832 + t] = (b3[t] - m3[t]) * a + be3[t]; }
}

// ---------------- weight repack fp32 OIHW -> bf16
// w2b/w3b: [off][co][ci]; w1b: [co][ci] (1x1 conv)
__global__ __launch_bounds__(256) void wprep(const float* __restrict__ w2, const float* __restrict__ w3,
                                             const float* __restrict__ w1,
                                             ushort* __restrict__ w2b, ushort* __restrict__ w3b,
                                             ushort* __restrict__ w1b) {
    int t = blockIdx.x * 256 + threadIdx.x;
    if (t < 9 * 128 * 256) {
        int off = t >> 15; int r = t & 32767; int co = r >> 8; int ci = r & 255;
        w2b[t] = f2b(w2[(co * 256 + ci) * 9 + off]);
    }
    t -= 9 * 128 * 256;
    if (t >= 0 && t < 9 * 64 * 128) {
        int off = t >> 13; int r = t & 8191; int co = r >> 7; int ci = r & 127;
        w3b[t] = f2b(w3[(co * 128 + ci) * 9 + off]);
    }
    t -= 9 * 64 * 128;
    if (t >= 0 && t < 256 * 64) {
        w1b[t] = f2b(w1[t]);          // OIHW 1x1 == [co][ci] flat
    }
}

// ---------------- concat part 1 (runs LAST): out[b, 0:64] = input[b]
__global__ __launch_bounds__(256) void copy_in_k(const float* __restrict__ x, float* __restrict__ out) {
    size_t i = (size_t)blockIdx.x * 256 + threadIdx.x;
    size_t b = i >> 18;
    size_t r = i & 262143;
    ((float4*)out)[b * (size_t)(128 * HW / 4) + r] = ((const float4*)x)[i];
}

// ---------------- conv1x1 (64 -> 256) + BN + ReLU via MFMA, bf16 hi/lo split of x
// B-fragments loaded straight from global NCHW (lane=px), no x-LDS, no transpose.
// Round-5: epilogue goes through LDS (reusing sW) so global stores are
// coalesced int4 (old path: scattered 8B ushort4 -> HBM write amplification).
__global__ __launch_bounds__(256, 2)
void conv1_mfma(const float* __restrict__ x, const ushort* __restrict__ w1b,
                const float* __restrict__ alpha, const float* __restrict__ beta,
                ushort* __restrict__ c1u, int b0) {
    __shared__ __align__(16) ushort sW[256][72];   // [co][ci pad72] = 36 KB; reused as epilogue staging
    const int tid = threadIdx.x;
    const int lane = tid & 63;
    const int wid = tid >> 6;          // 4 waves, each owns 32 px
    const int l31 = lane & 31;
    const int l5 = lane >> 5;
    const int bz = blockIdx.x >> 7;    // chunk-local batch 0..7
    const int y  = blockIdx.x & 127;
    const int px = wid * 32 + l31;

    // stage weights: 256x64 bf16 = 2048 int4, 8 per thread
#pragma unroll
    for (int it = 0; it < 8; ++it) {
        const int idx = it * 256 + tid;
        const int co = idx >> 3, cig = idx & 7;
        *(int4*)&sW[co][cig * 8] = *(const int4*)&w1b[co * 64 + cig * 8];
    }

    // load x B-fragments: ci = s*16 + l5*8 + j, col = px.  32 coalesced dwords.
    const float* xp = x + ((size_t)(b0 + bz) * 64 + l5 * 8) * HW + y * 128 + px;
    float xv[32];
#pragma unroll
    for (int s = 0; s < 4; ++s)
#pragma unroll
        for (int j = 0; j < 8; ++j)
            xv[s * 8 + j] = xp[(size_t)(s * 16 + j) * HW];

    // split fp32 -> bf16 hi (trunc) + lo (RNE of remainder)
    union { ushort u[8]; s8v v; } hf[4], lf[4];
#pragma unroll
    for (int s = 0; s < 4; ++s)
#pragma unroll
        for (int j = 0; j < 8; ++j) {
            union { float f; unsigned u; } t0; t0.f = xv[s * 8 + j];
            hf[s].u[j] = (ushort)(t0.u >> 16);
            union { unsigned u; float f; } t1; t1.u = t0.u & 0xFFFF0000u;
            lf[s].u[j] = f2b(t0.f - t1.f);
        }

    f16v acc[8];
#pragma unroll
    for (int ct = 0; ct < 8; ++ct) acc[ct] = (f16v)(0.0f);

    __syncthreads();
#pragma unroll
    for (int s = 0; s < 4; ++s) {
#pragma unroll
        for (int ct = 0; ct < 8; ++ct) {
            const s8v af = *(const s8v*)&sW[ct * 32 + l31][s * 16 + l5 * 8];
            acc[ct] = __builtin_amdgcn_mfma_f32_32x32x16_bf16(af, hf[s].v, acc[ct], 0, 0, 0);
            acc[ct] = __builtin_amdgcn_mfma_f32_32x32x16_bf16(af, lf[s].v, acc[ct], 0, 0, 0);
        }
    }

    // epilogue: BN+ReLU -> LDS (pad-136 rows, reusing sW) -> coalesced int4 stores.
    // pass p covers co p*128 .. p*128+127 (128 px x 136 x 2B = 34.8 KB <= 36.9 KB)
    ushort* sT = &sW[0][0];
    const int piece = y >> 6;
    const size_t base = (size_t)(2 * bz + piece) * 4194304 + (size_t)(y & 63) * 128 * 256;
#pragma unroll
    for (int p = 0; p < 2; ++p) {
        __syncthreads();           // sW reads (p=0) / prior drain (p=1) complete
#pragma unroll
        for (int c4 = 0; c4 < 4; ++c4) {
            const int ct = p * 4 + c4;
#pragma unroll
            for (int rg = 0; rg < 4; ++rg) {
                const int co = c4 * 32 + rg * 8 + l5 * 4;       // 0..127
                const float4 av = *(const float4*)&alpha[p * 128 + co];
                const float4 bv = *(const float4*)&beta[p * 128 + co];
                ushort4 o;
                o.x = f2b(fmaxf(acc[ct][rg * 4 + 0] * av.x + bv.x, 0.f));
                o.y = f2b(fmaxf(acc[ct][rg * 4 + 1] * av.y + bv.y, 0.f));
                o.z = f2b(fmaxf(acc[ct][rg * 4 + 2] * av.z + bv.z, 0.f));
                o.w = f2b(fmaxf(acc[ct][rg * 4 + 3] * av.w + bv.w, 0.f));
                *(ushort4*)&sT[px * 136 + co] = o;
            }
        }
        __syncthreads();
        // drain: 128 px x 128 co = 2048 int4, 8/thread, coalesced 256B/wave segs
#pragma unroll
        for (int it = 0; it < 8; ++it) {
            const int idx = it * 256 + tid;
            const int pxx = idx >> 4, c16 = idx & 15;
            const int4 v = *(const int4*)&sT[pxx * 136 + c16 * 8];
            *(int4*)&c1u[base + (size_t)pxx * 256 + p * 128 + c16 * 8] = v;
        }
    }
}

// ---------------- conv2: 3x3, 256->128, implicit-GEMM MFMA (bf16)
// Round-3 shape (CO=128/block, 2 blk/CU) + Round-5 T14 async-STAGE split:
// next section's global loads issue into regs BEFORE the MFMA block; the
// L2 latency + vmcnt drain hides under ~48 MFMA/wave instead of sitting
// naked between barriers.
__global__ __launch_bounds__(256, 2)
void conv2_mfma(const ushort* __restrict__ c1u, const ushort* __restrict__ wb,
                const float* __restrict__ alpha, const float* __restrict__ beta,
                ushort* __restrict__ ybf, int b0) {
    constexpr int CI = 256, CO = 128, MT = 2;
    __shared__ __align__(16) ushort sX[2][130][40];     // [row][px+1][ci32 pad40]  20.8 KB
    __shared__ __align__(16) ushort sW[3][CO][40];      // [dx][co][ci32 pad40]     30.7 KB
    const int tid = threadIdx.x;
    const int lane = tid & 63;
    const int wid = tid >> 6;
    const int wm = wid & 1;
    const int wr = wid >> 1;
    const int l31 = lane & 31;
    const int l5 = lane >> 5;
    const int bz = blockIdx.x >> 6;                   // chunk-local batch 0..7
    const int y0 = (blockIdx.x & 63) * 2;

    f16v acc[MT][4];
#pragma unroll
    for (int mt = 0; mt < MT; ++mt)
#pragma unroll
        for (int nt = 0; nt < 4; ++nt) acc[mt][nt] = (f16v)(0.0f);

    if (tid < 128) {       // zero x-halo pads (cols 0..31 used) once
        int r = tid >> 6, rem = tid & 63;
        int p = (rem < 32) ? 0 : 129;
        sX[r][p][rem & 31] = 0;
    }

    // per-thread staging coords (static)
    int4 xv[4], wv[6];

#define C2_LOADS(S) {                                                          \
        const int dy_ = (S) >> 3, cc_ = ((S) & 7) * 32;                        \
        _Pragma("unroll")                                                      \
        for (int it = 0; it < 4; ++it) {                                       \
            const int idx = it * 256 + tid;                                    \
            const int r = idx >> 9, xx = (idx >> 2) & 127, cig = idx & 3;      \
            const int yy = y0 + r + dy_ - 1;                                   \
            int4 v = make_int4(0, 0, 0, 0);                                    \
            if ((unsigned)yy < 128u) {                                         \
                const size_t gb = (size_t)(2 * bz + (yy >> 6)) * 4194304;      \
                v = *(const int4*)&c1u[gb + (((yy & 63) * 128 + xx) * 256 + cc_ + cig * 8)]; \
            }                                                                  \
            xv[it] = v;                                                        \
        }                                                                      \
        _Pragma("unroll")                                                      \
        for (int it = 0; it < 6; ++it) {                                       \
            const int idx = it * 256 + tid;                                    \
            const int dxs = idx >> 9;                                          \
            const int r = idx & 511;                                           \
            const int co = r >> 2, cig = r & 3;                                \
            wv[it] = *(const int4*)&wb[((size_t)((dy_ * 3 + dxs) * CO) + co) * CI + cc_ + cig * 8]; \
        }                                                                      \
    }

#define C2_WRITES() {                                                          \
        _Pragma("unroll")                                                      \
        for (int it = 0; it < 4; ++it) {                                       \
            const int idx = it * 256 + tid;                                    \
            const int r = idx >> 9, xx = (idx >> 2) & 127, cig = idx & 3;      \
            *(int4*)&sX[r][xx + 1][cig * 8] = xv[it];                          \
        }                                                                      \
        _Pragma("unroll")                                                      \
        for (int it = 0; it < 6; ++it) {                                       \
            const int idx = it * 256 + tid;                                    \
            const int dxs = idx >> 9;                                          \
            const int r = idx & 511;                                           \
            const int co = r >> 2, cig = r & 3;                                \
            *(int4*)&sW[dxs][co][cig * 8] = wv[it];                            \
        }                                                                      \
    }

    C2_LOADS(0);
    __syncthreads();                 // halo pads visible
    C2_WRITES();
    __syncthreads();

    for (int s = 0; s < 24; ++s) {
        if (s < 23) C2_LOADS(s + 1);         // prefetch under MFMA
#pragma unroll
        for (int dx = 0; dx < 3; ++dx) {
#pragma unroll
            for (int kh = 0; kh < 2; ++kh) {
                s8v af[MT], bfr[4];
#pragma unroll
                for (int mt = 0; mt < MT; ++mt)
                    af[mt] = *(const s8v*)&sW[dx][wm * 64 + mt * 32 + l31][kh * 16 + l5 * 8];
#pragma unroll
                for (int nt = 0; nt < 4; ++nt)
                    bfr[nt] = *(const s8v*)&sX[wr][nt * 32 + l31 + dx][kh * 16 + l5 * 8];
#pragma unroll
                for (int mt = 0; mt < MT; ++mt)
#pragma unroll
                    for (int nt = 0; nt < 4; ++nt)
                        acc[mt][nt] = __builtin_amdgcn_mfma_f32_32x32x16_bf16(
                            af[mt], bfr[nt], acc[mt][nt], 0, 0, 0);
            }
        }
        if (s < 23) {
            __syncthreads();                 // all reads of buf done
            C2_WRITES();                     // vmcnt satisfied during MFMA
            __syncthreads();
        }
    }
#undef C2_LOADS
#undef C2_WRITES

    const int yy = y0 + wr;
    const size_t cb2 = (size_t)(b0 + bz) * 4194304 + 2097152;   // B-half ushort base
#pragma unroll
    for (int mt = 0; mt < MT; ++mt) {
#pragma unroll
        for (int nt = 0; nt < 4; ++nt) {
            const int xx = nt * 32 + l31;
#pragma unroll
            for (int rg = 0; rg < 4; ++rg) {
                const int co0 = wm * 64 + mt * 32 + rg * 8 + l5 * 4;
                const float4 av = *(const float4*)&alpha[co0];
                const float4 bv = *(const float4*)&beta[co0];
                ushort4 o;
                o.x = f2b(fmaxf(acc[mt][nt][rg * 4 + 0] * av.x + bv.x, 0.f));
                o.y = f2b(fmaxf(acc[mt][nt][rg * 4 + 1] * av.y + bv.y, 0.f));
                o.z = f2b(fmaxf(acc[mt][nt][rg * 4 + 2] * av.z + bv.z, 0.f));
                o.w = f2b(fmaxf(acc[mt][nt][rg * 4 + 3] * av.w + bv.w, 0.f));
                *(ushort4*)&ybf[cb2 + ((size_t)yy * 128 + xx) * 128 + co0] = o;
            }
        }
    }
}

// ---------------- sobel depthwise, c2 (out B-half) -> edge (out A-half), bf16 NHWC
__global__ __launch_bounds__(256)
void sobel_nhwc(const ushort* __restrict__ outu, ushort* __restrict__ edgeu) {
    const int tid = threadIdx.x;
    const int cg = tid & 15;        // 8-channel group
    const int xl = tid >> 4;        // 16 px per block
    const int xblk = blockIdx.x & 7;
    const int y = (blockIdx.x >> 3) & 127;
    const int b = blockIdx.x >> 10;
    const int x = xblk * 16 + xl;
    const size_t cb2 = (size_t)b * 4194304 + 2097152;
    const size_t eb = (size_t)b * 4194304;
    float acc[8];
#pragma unroll
    for (int j = 0; j < 8; ++j) acc[j] = 0.f;
    const float cf[9] = {2.f, 4.f, 4.f, -2.f, 0.f, 2.f, -4.f, -4.f, -2.f};
#pragma unroll
    for (int t = 0; t < 9; ++t) {
        if (t == 4) continue;
        const int yy = y + (t / 3) - 1, xx = x + (t % 3) - 1;
        if ((unsigned)yy < 128u && (unsigned)xx < 128u) {
            union { int4 v; ushort s[8]; } u;
            u.v = *(const int4*)&outu[cb2 + ((size_t)yy * 128 + xx) * 128 + cg * 8];
            const float c = cf[t];
#pragma unroll
            for (int j = 0; j < 8; ++j) acc[j] += c * b2f(u.s[j]);
        }
    }
    union { ushort s[8]; int4 v; } o;
#pragma unroll
    for (int j = 0; j < 8; ++j) o.s[j] = f2b(acc[j]);
    *(int4*)&edgeu[eb + ((size_t)y * 128 + x) * 128 + cg * 8] = o.v;
}

// ---------------- conv3: 3x3, 128->64, implicit-GEMM MFMA; edge (out A-half) -> out fp32 ch64:128
// Round-3 version (cc step 64, 12 barrier sections, 48 MFMA/wave per section).
__global__ __launch_bounds__(256, 2)
void conv3_mfma(const ushort* __restrict__ edgeu, const ushort* __restrict__ wb,
                const float* __restrict__ alpha, const float* __restrict__ beta,
                float* __restrict__ out) {
    constexpr int CI = 128, CO = 64;
    __shared__ __align__(16) ushort sX[2][130][72];     // [row][px+1][ci64 pad72] 37.4 KB
    __shared__ __align__(16) ushort sW[3][CO][72];      // [dx][co][ci64 pad72]    27.6 KB
    const int tid = threadIdx.x;
    const int lane = tid & 63;
    const int wid = tid >> 6;
    const int wm = wid & 1;        // co half (32)
    const int wr = wid >> 1;       // row
    const int l31 = lane & 31;
    const int l5 = lane >> 5;
    const int b = blockIdx.x >> 6;
    const int y0 = (blockIdx.x & 63) * 2;
    const size_t eb = (size_t)b * 4194304;

    f16v acc[4];
#pragma unroll
    for (int nt = 0; nt < 4; ++nt) acc[nt] = (f16v)(0.0f);

    {   // zero x-halo pads (cols 0..63 used): 2 rows x 2 pads x 64 = 256 tasks
        int r = tid >> 7, rem = tid & 127;
        int p = (rem < 64) ? 0 : 129;
        sX[r][p][rem & 63] = 0;
    }

    for (int dy = 0; dy < 3; ++dy) {
        for (int cc = 0; cc < CI; cc += 64) {
            __syncthreads();
            // stage X: 2 rows x 128 px x 64 ci (2048 int4, 8/thread)
#pragma unroll
            for (int it = 0; it < 8; ++it) {
                const int idx = it * 256 + tid;
                const int r = idx >> 10, xx = (idx >> 3) & 127, cig = idx & 7;
                const int yy = y0 + r + dy - 1;
                int4 v = make_int4(0, 0, 0, 0);
                if ((unsigned)yy < 128u)
                    v = *(const int4*)&edgeu[eb + ((size_t)yy * 128 + xx) * CI + cc + cig * 8];
                *(int4*)&sX[r][xx + 1][cig * 8] = v;
            }
            // stage W: 3 dx slices x 64 co x 64 ci (1536 int4, 6/thread)
#pragma unroll
            for (int it = 0; it < 6; ++it) {
                const int idx = it * 256 + tid;
                const int dxs = idx >> 9;           // 0..2
                const int r = idx & 511;
                const int co = r >> 3, cig = r & 7;
                *(int4*)&sW[dxs][co][cig * 8] =
                    *(const int4*)&wb[((size_t)((dy * 3 + dxs) * CO) + co) * CI + cc + cig * 8];
            }
            __syncthreads();
#pragma unroll
            for (int dx = 0; dx < 3; ++dx) {
#pragma unroll
                for (int kh = 0; kh < 4; ++kh) {
                    const s8v af = *(const s8v*)&sW[dx][wm * 32 + l31][kh * 16 + l5 * 8];
                    s8v bfr[4];
#pragma unroll
                    for (int nt = 0; nt < 4; ++nt)
                        bfr[nt] = *(const s8v*)&sX[wr][nt * 32 + l31 + dx][kh * 16 + l5 * 8];
#pragma unroll
                    for (int nt = 0; nt < 4; ++nt)
                        acc[nt] = __builtin_amdgcn_mfma_f32_32x32x16_bf16(af, bfr[nt], acc[nt], 0, 0, 0);
                }
            }
        }
    }
    const int yy = y0 + wr;
#pragma unroll
    for (int nt = 0; nt < 4; ++nt) {
        const int xx = nt * 32 + l31;
#pragma unroll
        for (int rg = 0; rg < 4; ++rg) {
            const int co0 = wm * 32 + rg * 8 + l5 * 4;
            const float4 av = *(const float4*)&alpha[co0];
            const float4 bv = *(const float4*)&beta[co0];
            const size_t base = ((size_t)b * 128 + 64 + co0) * HW + yy * 128 + xx;
            out[base]          = fmaxf(acc[nt][rg * 4 + 0] * av.x + bv.x, 0.f);
            out[base + HW]     = fmaxf(acc[nt][rg * 4 + 1] * av.y + bv.y, 0.f);
            out[base + 2 * HW] = fmaxf(acc[nt][rg * 4 + 2] * av.z + bv.z, 0.f);
            out[base + 3 * HW] = fmaxf(acc[nt][rg * 4 + 3] * av.w + bv.w, 0.f);
        }
    }
}

extern "C" void kernel_launch(void* const* d_in, const int* in_sizes, int n_in,
                              void* d_out, int out_size, void* d_ws, size_t ws_size,
                              hipStream_t stream) {
    const float* input = (const float*)d_in[0];
    const float* w1 = (const float*)d_in[1];
    const float* b1 = (const float*)d_in[2];
    const float* g1 = (const float*)d_in[3];
    const float* be1 = (const float*)d_in[4];
    const float* m1 = (const float*)d_in[5];
    const float* v1 = (const float*)d_in[6];
    const float* w2 = (const float*)d_in[7];
    const float* b2 = (const float*)d_in[8];
    const float* g2 = (const float*)d_in[9];
    const float* be2 = (const float*)d_in[10];
    const float* m2 = (const float*)d_in[11];
    const float* v2 = (const float*)d_in[12];
    const float* w3 = (const float*)d_in[13];
    const float* b3 = (const float*)d_in[14];
    const float* g3 = (const float*)d_in[15];
    const float* be3 = (const float*)d_in[16];
    const float* m3 = (const float*)d_in[17];
    const float* v3 = (const float*)d_in[18];
    float* ws = (float*)d_ws;
    float* out = (float*)d_out;
    ushort* outu = (ushort*)d_out;

    float* A1 = ws;        float* B1 = ws + 256;
    float* A2 = ws + 512;  float* B2 = ws + 640;
    float* A3 = ws + 768;  float* B3 = ws + 832;

    char* wsb = (char*)d_ws;
    ushort* w1b = (ushort*)(wsb + 4096);                           // 32768 B
    ushort* w2b = (ushort*)(wsb + 4096 + 32768);                   // 589824 B
    ushort* w3b = (ushort*)(wsb + 4096 + 32768 + 589824);          // 147456 B; total < 1 MB

    bn_prep<<<1, 256, 0, stream>>>(b1, g1, be1, m1, v1, b2, g2, be2, m2, v2,
                                   b3, g3, be3, m3, v3, ws);
    wprep<<<1505, 256, 0, stream>>>(w2, w3, w1, w2b, w3b, w1b);

    // phase A: c1 -> out A-halves (8 batches/iter), c2 -> out B-halves
    for (int b0 = 0; b0 < 16; b0 += 8) {
        conv1_mfma<<<1024, 256, 0, stream>>>(input, w1b, A1, B1, outu, b0);
        conv2_mfma<<<512, 256, 0, stream>>>(outu, w2b, A2, B2, outu, b0);
    }
    // phase B: full-batch fat dispatches
    sobel_nhwc<<<16384, 256, 0, stream>>>(outu, outu);
    conv3_mfma<<<1024, 256, 0, stream>>>(outu, w3b, A3, B3, out);
    copy_in_k<<<16384, 256, 0, stream>>>(input, out);
}

// Round 7
// 499.448 us; speedup vs baseline: 1.1966x; 1.1966x over previous
//
#include <hip/hip_runtime.h>

#define HW 16384
#define EPSF 1e-5f

typedef __attribute__((ext_vector_type(8))) short s8v;     // 8 bf16 (4 VGPRs)
typedef __attribute__((ext_vector_type(16))) float f16v;   // 32x32 accum

__device__ __forceinline__ ushort f2b(float f) {           // fp32 -> bf16 RNE
    union { float f; unsigned u; } v; v.f = f;
    return (ushort)((v.u + 0x7FFFu + ((v.u >> 16) & 1u)) >> 16);
}
__device__ __forceinline__ float b2f(ushort h) {
    union { unsigned u; float f; } v; v.u = ((unsigned)h) << 16; return v.f;
}

// out-region map (ushort offsets into d_out):
//   A-half of out-batch k (ch 0:64):   k*4194304 .. +2097152 ushorts (4 MB)
//   B-half of out-batch k (ch 64:128): k*4194304 + 2097152 (4 MB)
// c1[local j] (8 MB) -> A-halves of out-batches 2j, 2j+1 (row piece = y>>6)
// c2[b] bf16 NHWC    -> B-half of batch b
// edge[b] bf16 NHWC  -> A-half of batch b (after c1 dead)

// ---------------- BN folding
__global__ void bn_prep(const float* __restrict__ b1, const float* __restrict__ g1,
                        const float* __restrict__ be1, const float* __restrict__ m1,
                        const float* __restrict__ v1,
                        const float* __restrict__ b2, const float* __restrict__ g2,
                        const float* __restrict__ be2, const float* __restrict__ m2,
                        const float* __restrict__ v2,
                        const float* __restrict__ b3, const float* __restrict__ g3,
                        const float* __restrict__ be3, const float* __restrict__ m3,
                        const float* __restrict__ v3,
                        float* __restrict__ ws) {
    int t = threadIdx.x;
    if (t < 256) { float a = g1[t] * rsqrtf(v1[t] + EPSF); ws[t] = a;       ws[256 + t] = (b1[t] - m1[t]) * a + be1[t]; }
    if (t < 128) { float a = g2[t] * rsqrtf(v2[t] + EPSF); ws[512 + t] = a; ws[640 + t] = (b2[t] - m2[t]) * a + be2[t]; }
    if (t < 64)  { float a = g3[t] * rsqrtf(v3[t] + EPSF); ws[768 + t] = a; ws[832 + t] = (b3[t] - m3[t]) * a + be3[t]; }
}

// ---------------- weight repack fp32 OIHW -> bf16
// w2b/w3b: [off][co][ci]; w1b: [co][ci] (1x1 conv)
__global__ __launch_bounds__(256) void wprep(const float* __restrict__ w2, const float* __restrict__ w3,
                                             const float* __restrict__ w1,
                                             ushort* __restrict__ w2b, ushort* __restrict__ w3b,
                                             ushort* __restrict__ w1b) {
    int t = blockIdx.x * 256 + threadIdx.x;
    if (t < 9 * 128 * 256) {
        int off = t >> 15; int r = t & 32767; int co = r >> 8; int ci = r & 255;
        w2b[t] = f2b(w2[(co * 256 + ci) * 9 + off]);
    }
    t -= 9 * 128 * 256;
    if (t >= 0 && t < 9 * 64 * 128) {
        int off = t >> 13; int r = t & 8191; int co = r >> 7; int ci = r & 127;
        w3b[t] = f2b(w3[(co * 128 + ci) * 9 + off]);
    }
    t -= 9 * 64 * 128;
    if (t >= 0 && t < 256 * 64) {
        w1b[t] = f2b(w1[t]);          // OIHW 1x1 == [co][ci] flat
    }
}

// ---------------- concat part 1 (runs LAST): out[b, 0:64] = input[b]
__global__ __launch_bounds__(256) void copy_in_k(const float* __restrict__ x, float* __restrict__ out) {
    size_t i = (size_t)blockIdx.x * 256 + threadIdx.x;
    size_t b = i >> 18;
    size_t r = i & 262143;
    ((float4*)out)[b * (size_t)(128 * HW / 4) + r] = ((const float4*)x)[i];
}

// ---------------- conv1x1 (64 -> 256) + BN + ReLU via MFMA, bf16 hi/lo split of x
// B-fragments loaded straight from global NCHW (lane=px), no x-LDS, no transpose.
// LDS-staged epilogue (Round-5 win, ~-40 us/dispatch): coalesced int4 stores.
__global__ __launch_bounds__(256, 2)
void conv1_mfma(const float* __restrict__ x, const ushort* __restrict__ w1b,
                const float* __restrict__ alpha, const float* __restrict__ beta,
                ushort* __restrict__ c1u, int b0) {
    __shared__ __align__(16) ushort sW[256][72];   // [co][ci pad72] = 36 KB; reused as epilogue staging
    const int tid = threadIdx.x;
    const int lane = tid & 63;
    const int wid = tid >> 6;          // 4 waves, each owns 32 px
    const int l31 = lane & 31;
    const int l5 = lane >> 5;
    const int bz = blockIdx.x >> 7;    // chunk-local batch 0..7
    const int y  = blockIdx.x & 127;
    const int px = wid * 32 + l31;

    // stage weights: 256x64 bf16 = 2048 int4, 8 per thread
#pragma unroll
    for (int it = 0; it < 8; ++it) {
        const int idx = it * 256 + tid;
        const int co = idx >> 3, cig = idx & 7;
        *(int4*)&sW[co][cig * 8] = *(const int4*)&w1b[co * 64 + cig * 8];
    }

    // load x B-fragments: ci = s*16 + l5*8 + j, col = px.  32 coalesced dwords.
    const float* xp = x + ((size_t)(b0 + bz) * 64 + l5 * 8) * HW + y * 128 + px;
    float xv[32];
#pragma unroll
    for (int s = 0; s < 4; ++s)
#pragma unroll
        for (int j = 0; j < 8; ++j)
            xv[s * 8 + j] = xp[(size_t)(s * 16 + j) * HW];

    // split fp32 -> bf16 hi (trunc) + lo (RNE of remainder)
    union { ushort u[8]; s8v v; } hf[4], lf[4];
#pragma unroll
    for (int s = 0; s < 4; ++s)
#pragma unroll
        for (int j = 0; j < 8; ++j) {
            union { float f; unsigned u; } t0; t0.f = xv[s * 8 + j];
            hf[s].u[j] = (ushort)(t0.u >> 16);
            union { unsigned u; float f; } t1; t1.u = t0.u & 0xFFFF0000u;
            lf[s].u[j] = f2b(t0.f - t1.f);
        }

    f16v acc[8];
#pragma unroll
    for (int ct = 0; ct < 8; ++ct) acc[ct] = (f16v)(0.0f);

    __syncthreads();
#pragma unroll
    for (int s = 0; s < 4; ++s) {
#pragma unroll
        for (int ct = 0; ct < 8; ++ct) {
            const s8v af = *(const s8v*)&sW[ct * 32 + l31][s * 16 + l5 * 8];
            acc[ct] = __builtin_amdgcn_mfma_f32_32x32x16_bf16(af, hf[s].v, acc[ct], 0, 0, 0);
            acc[ct] = __builtin_amdgcn_mfma_f32_32x32x16_bf16(af, lf[s].v, acc[ct], 0, 0, 0);
        }
    }

    // epilogue: BN+ReLU -> LDS (pad-136 rows, reusing sW) -> coalesced int4 stores.
    // pass p covers co p*128 .. p*128+127 (128 px x 136 x 2B = 34.8 KB <= 36.9 KB)
    ushort* sT = &sW[0][0];
    const int piece = y >> 6;
    const size_t base = (size_t)(2 * bz + piece) * 4194304 + (size_t)(y & 63) * 128 * 256;
#pragma unroll
    for (int p = 0; p < 2; ++p) {
        __syncthreads();           // sW reads (p=0) / prior drain (p=1) complete
#pragma unroll
        for (int c4 = 0; c4 < 4; ++c4) {
            const int ct = p * 4 + c4;
#pragma unroll
            for (int rg = 0; rg < 4; ++rg) {
                const int co = c4 * 32 + rg * 8 + l5 * 4;       // 0..127
                const float4 av = *(const float4*)&alpha[p * 128 + co];
                const float4 bv = *(const float4*)&beta[p * 128 + co];
                ushort4 o;
                o.x = f2b(fmaxf(acc[ct][rg * 4 + 0] * av.x + bv.x, 0.f));
                o.y = f2b(fmaxf(acc[ct][rg * 4 + 1] * av.y + bv.y, 0.f));
                o.z = f2b(fmaxf(acc[ct][rg * 4 + 2] * av.z + bv.z, 0.f));
                o.w = f2b(fmaxf(acc[ct][rg * 4 + 3] * av.w + bv.w, 0.f));
                *(ushort4*)&sT[px * 136 + co] = o;
            }
        }
        __syncthreads();
        // drain: 128 px x 128 co = 2048 int4, 8/thread, coalesced 256B/wave segs
#pragma unroll
        for (int it = 0; it < 8; ++it) {
            const int idx = it * 256 + tid;
            const int pxx = idx >> 4, c16 = idx & 15;
            const int4 v = *(const int4*)&sT[pxx * 136 + c16 * 8];
            *(int4*)&c1u[base + (size_t)pxx * 256 + p * 128 + c16 * 8] = v;
        }
    }
}

// ---------------- conv2: 3x3, 256->128, implicit-GEMM MFMA (bf16)
// Round-3-exact body (best measured: 96.4 us/dispatch, VGPR 120, no spill).
// NOTE: register-prefetch (T14) is infeasible here: acc = 128 AGPR + ~120 VGPR
// is already at the 256-reg unified-file cap for 2 waves/SIMD; any prefetch
// state spills to scratch (Round-5: WRITE_SIZE 39 -> 308 MB, +53 us).
__global__ __launch_bounds__(256, 2)
void conv2_mfma(const ushort* __restrict__ c1u, const ushort* __restrict__ wb,
                const float* __restrict__ alpha, const float* __restrict__ beta,
                ushort* __restrict__ ybf, int b0) {
    constexpr int CI = 256, CO = 128, MT = 2;
    __shared__ __align__(16) ushort sX[2][130][40];     // [row][px+1][ci32 pad40]  20.8 KB
    __shared__ __align__(16) ushort sW[3][CO][40];      // [dx][co][ci32 pad40]     30.7 KB
    const int tid = threadIdx.x;
    const int lane = tid & 63;
    const int wid = tid >> 6;
    const int wm = wid & 1;
    const int wr = wid >> 1;
    const int l31 = lane & 31;
    const int l5 = lane >> 5;
    const int bz = blockIdx.x >> 6;                   // chunk-local batch 0..7
    const int y0 = (blockIdx.x & 63) * 2;

    f16v acc[MT][4];
#pragma unroll
    for (int mt = 0; mt < MT; ++mt)
#pragma unroll
        for (int nt = 0; nt < 4; ++nt) acc[mt][nt] = (f16v)(0.0f);

    if (tid < 128) {       // zero x-halo pads (cols 0..31 used) once
        int r = tid >> 6, rem = tid & 63;
        int p = (rem < 32) ? 0 : 129;
        sX[r][p][rem & 31] = 0;
    }

    for (int dy = 0; dy < 3; ++dy) {
        for (int cc = 0; cc < CI; cc += 32) {
            __syncthreads();
            // stage X: 2 rows x 128 px x 32 ci  (1024 int4, 4/thread)
#pragma unroll
            for (int it = 0; it < 4; ++it) {
                const int idx = it * 256 + tid;
                const int r = idx >> 9, xx = (idx >> 2) & 127, cig = idx & 3;
                const int yy = y0 + r + dy - 1;
                int4 v = make_int4(0, 0, 0, 0);
                if ((unsigned)yy < 128u) {
                    const size_t base = (size_t)(2 * bz + (yy >> 6)) * 4194304;
                    v = *(const int4*)&c1u[base + (((yy & 63) * 128 + xx) * 256 + cc + cig * 8)];
                }
                *(int4*)&sX[r][xx + 1][cig * 8] = v;
            }
            // stage W: 3 dx slices x 128 co x 32 ci (1536 int4, 6/thread)
#pragma unroll
            for (int it = 0; it < 6; ++it) {
                const int idx = it * 256 + tid;
                const int dxs = idx >> 9;           // 0..2
                const int r = idx & 511;
                const int co = r >> 2, cig = r & 3;
                *(int4*)&sW[dxs][co][cig * 8] =
                    *(const int4*)&wb[((size_t)((dy * 3 + dxs) * CO) + co) * CI + cc + cig * 8];
            }
            __syncthreads();
#pragma unroll
            for (int dx = 0; dx < 3; ++dx) {
#pragma unroll
                for (int kh = 0; kh < 2; ++kh) {
                    s8v af[MT], bfr[4];
#pragma unroll
                    for (int mt = 0; mt < MT; ++mt)
                        af[mt] = *(const s8v*)&sW[dx][wm * 64 + mt * 32 + l31][kh * 16 + l5 * 8];
#pragma unroll
                    for (int nt = 0; nt < 4; ++nt)
                        bfr[nt] = *(const s8v*)&sX[wr][nt * 32 + l31 + dx][kh * 16 + l5 * 8];
#pragma unroll
                    for (int mt = 0; mt < MT; ++mt)
#pragma unroll
                        for (int nt = 0; nt < 4; ++nt)
                            acc[mt][nt] = __builtin_amdgcn_mfma_f32_32x32x16_bf16(
                                af[mt], bfr[nt], acc[mt][nt], 0, 0, 0);
                }
            }
        }
    }
    const int yy = y0 + wr;
    const size_t cb2 = (size_t)(b0 + bz) * 4194304 + 2097152;   // B-half ushort base
#pragma unroll
    for (int mt = 0; mt < MT; ++mt) {
#pragma unroll
        for (int nt = 0; nt < 4; ++nt) {
            const int xx = nt * 32 + l31;
#pragma unroll
            for (int rg = 0; rg < 4; ++rg) {
                const int co0 = wm * 64 + mt * 32 + rg * 8 + l5 * 4;
                const float4 av = *(const float4*)&alpha[co0];
                const float4 bv = *(const float4*)&beta[co0];
                ushort4 o;
                o.x = f2b(fmaxf(acc[mt][nt][rg * 4 + 0] * av.x + bv.x, 0.f));
                o.y = f2b(fmaxf(acc[mt][nt][rg * 4 + 1] * av.y + bv.y, 0.f));
                o.z = f2b(fmaxf(acc[mt][nt][rg * 4 + 2] * av.z + bv.z, 0.f));
                o.w = f2b(fmaxf(acc[mt][nt][rg * 4 + 3] * av.w + bv.w, 0.f));
                *(ushort4*)&ybf[cb2 + ((size_t)yy * 128 + xx) * 128 + co0] = o;
            }
        }
    }
}

// ---------------- sobel depthwise, c2 (out B-half) -> edge (out A-half), bf16 NHWC
__global__ __launch_bounds__(256)
void sobel_nhwc(const ushort* __restrict__ outu, ushort* __restrict__ edgeu) {
    const int tid = threadIdx.x;
    const int cg = tid & 15;        // 8-channel group
    const int xl = tid >> 4;        // 16 px per block
    const int xblk = blockIdx.x & 7;
    const int y = (blockIdx.x >> 3) & 127;
    const int b = blockIdx.x >> 10;
    const int x = xblk * 16 + xl;
    const size_t cb2 = (size_t)b * 4194304 + 2097152;
    const size_t eb = (size_t)b * 4194304;
    float acc[8];
#pragma unroll
    for (int j = 0; j < 8; ++j) acc[j] = 0.f;
    const float cf[9] = {2.f, 4.f, 4.f, -2.f, 0.f, 2.f, -4.f, -4.f, -2.f};
#pragma unroll
    for (int t = 0; t < 9; ++t) {
        if (t == 4) continue;
        const int yy = y + (t / 3) - 1, xx = x + (t % 3) - 1;
        if ((unsigned)yy < 128u && (unsigned)xx < 128u) {
            union { int4 v; ushort s[8]; } u;
            u.v = *(const int4*)&outu[cb2 + ((size_t)yy * 128 + xx) * 128 + cg * 8];
            const float c = cf[t];
#pragma unroll
            for (int j = 0; j < 8; ++j) acc[j] += c * b2f(u.s[j]);
        }
    }
    union { ushort s[8]; int4 v; } o;
#pragma unroll
    for (int j = 0; j < 8; ++j) o.s[j] = f2b(acc[j]);
    *(int4*)&edgeu[eb + ((size_t)y * 128 + x) * 128 + cg * 8] = o.v;
}

// ---------------- conv3: 3x3, 128->64, implicit-GEMM MFMA; edge (out A-half) -> out fp32 ch64:128
// Round-3 version (cc step 64, 12 barrier sections, 48 MFMA/wave per section).
__global__ __launch_bounds__(256, 2)
void conv3_mfma(const ushort* __restrict__ edgeu, const ushort* __restrict__ wb,
                const float* __restrict__ alpha, const float* __restrict__ beta,
                float* __restrict__ out) {
    constexpr int CI = 128, CO = 64;
    __shared__ __align__(16) ushort sX[2][130][72];     // [row][px+1][ci64 pad72] 37.4 KB
    __shared__ __align__(16) ushort sW[3][CO][72];      // [dx][co][ci64 pad72]    27.6 KB
    const int tid = threadIdx.x;
    const int lane = tid & 63;
    const int wid = tid >> 6;
    const int wm = wid & 1;        // co half (32)
    const int wr = wid >> 1;       // row
    const int l31 = lane & 31;
    const int l5 = lane >> 5;
    const int b = blockIdx.x >> 6;
    const int y0 = (blockIdx.x & 63) * 2;
    const size_t eb = (size_t)b * 4194304;

    f16v acc[4];
#pragma unroll
    for (int nt = 0; nt < 4; ++nt) acc[nt] = (f16v)(0.0f);

    {   // zero x-halo pads (cols 0..63 used): 2 rows x 2 pads x 64 = 256 tasks
        int r = tid >> 7, rem = tid & 127;
        int p = (rem < 64) ? 0 : 129;
        sX[r][p][rem & 63] = 0;
    }

    for (int dy = 0; dy < 3; ++dy) {
        for (int cc = 0; cc < CI; cc += 64) {
            __syncthreads();
            // stage X: 2 rows x 128 px x 64 ci (2048 int4, 8/thread)
#pragma unroll
            for (int it = 0; it < 8; ++it) {
                const int idx = it * 256 + tid;
                const int r = idx >> 10, xx = (idx >> 3) & 127, cig = idx & 7;
                const int yy = y0 + r + dy - 1;
                int4 v = make_int4(0, 0, 0, 0);
                if ((unsigned)yy < 128u)
                    v = *(const int4*)&edgeu[eb + ((size_t)yy * 128 + xx) * CI + cc + cig * 8];
                *(int4*)&sX[r][xx + 1][cig * 8] = v;
            }
            // stage W: 3 dx slices x 64 co x 64 ci (1536 int4, 6/thread)
#pragma unroll
            for (int it = 0; it < 6; ++it) {
                const int idx = it * 256 + tid;
                const int dxs = idx >> 9;           // 0..2
                const int r = idx & 511;
                const int co = r >> 3, cig = r & 7;
                *(int4*)&sW[dxs][co][cig * 8] =
                    *(const int4*)&wb[((size_t)((dy * 3 + dxs) * CO) + co) * CI + cc + cig * 8];
            }
            __syncthreads();
#pragma unroll
            for (int dx = 0; dx < 3; ++dx) {
#pragma unroll
                for (int kh = 0; kh < 4; ++kh) {
                    const s8v af = *(const s8v*)&sW[dx][wm * 32 + l31][kh * 16 + l5 * 8];
                    s8v bfr[4];
#pragma unroll
                    for (int nt = 0; nt < 4; ++nt)
                        bfr[nt] = *(const s8v*)&sX[wr][nt * 32 + l31 + dx][kh * 16 + l5 * 8];
#pragma unroll
                    for (int nt = 0; nt < 4; ++nt)
                        acc[nt] = __builtin_amdgcn_mfma_f32_32x32x16_bf16(af, bfr[nt], acc[nt], 0, 0, 0);
                }
            }
        }
    }
    const int yy = y0 + wr;
#pragma unroll
    for (int nt = 0; nt < 4; ++nt) {
        const int xx = nt * 32 + l31;
#pragma unroll
        for (int rg = 0; rg < 4; ++rg) {
            const int co0 = wm * 32 + rg * 8 + l5 * 4;
            const float4 av = *(const float4*)&alpha[co0];
            const float4 bv = *(const float4*)&beta[co0];
            const size_t base = ((size_t)b * 128 + 64 + co0) * HW + yy * 128 + xx;
            out[base]          = fmaxf(acc[nt][rg * 4 + 0] * av.x + bv.x, 0.f);
            out[base + HW]     = fmaxf(acc[nt][rg * 4 + 1] * av.y + bv.y, 0.f);
            out[base + 2 * HW] = fmaxf(acc[nt][rg * 4 + 2] * av.z + bv.z, 0.f);
            out[base + 3 * HW] = fmaxf(acc[nt][rg * 4 + 3] * av.w + bv.w, 0.f);
        }
    }
}

extern "C" void kernel_launch(void* const* d_in, const int* in_sizes, int n_in,
                              void* d_out, int out_size, void* d_ws, size_t ws_size,
                              hipStream_t stream) {
    const float* input = (const float*)d_in[0];
    const float* w1 = (const float*)d_in[1];
    const float* b1 = (const float*)d_in[2];
    const float* g1 = (const float*)d_in[3];
    const float* be1 = (const float*)d_in[4];
    const float* m1 = (const float*)d_in[5];
    const float* v1 = (const float*)d_in[6];
    const float* w2 = (const float*)d_in[7];
    const float* b2 = (const float*)d_in[8];
    const float* g2 = (const float*)d_in[9];
    const float* be2 = (const float*)d_in[10];
    const float* m2 = (const float*)d_in[11];
    const float* v2 = (const float*)d_in[12];
    const float* w3 = (const float*)d_in[13];
    const float* b3 = (const float*)d_in[14];
    const float* g3 = (const float*)d_in[15];
    const float* be3 = (const float*)d_in[16];
    const float* m3 = (const float*)d_in[17];
    const float* v3 = (const float*)d_in[18];
    float* ws = (float*)d_ws;
    float* out = (float*)d_out;
    ushort* outu = (ushort*)d_out;

    float* A1 = ws;        float* B1 = ws + 256;
    float* A2 = ws + 512;  float* B2 = ws + 640;
    float* A3 = ws + 768;  float* B3 = ws + 832;

    char* wsb = (char*)d_ws;
    ushort* w1b = (ushort*)(wsb + 4096);                           // 32768 B
    ushort* w2b = (ushort*)(wsb + 4096 + 32768);                   // 589824 B
    ushort* w3b = (ushort*)(wsb + 4096 + 32768 + 589824);          // 147456 B; total < 1 MB

    bn_prep<<<1, 256, 0, stream>>>(b1, g1, be1, m1, v1, b2, g2, be2, m2, v2,
                                   b3, g3, be3, m3, v3, ws);
    wprep<<<1505, 256, 0, stream>>>(w2, w3, w1, w2b, w3b, w1b);

    // phase A: c1 -> out A-halves (8 batches/iter), c2 -> out B-halves
    for (int b0 = 0; b0 < 16; b0 += 8) {
        conv1_mfma<<<1024, 256, 0, stream>>>(input, w1b, A1, B1, outu, b0);
        conv2_mfma<<<512, 256, 0, stream>>>(outu, w2b, A2, B2, outu, b0);
    }
    // phase B: full-batch fat dispatches
    sobel_nhwc<<<16384, 256, 0, stream>>>(outu, outu);
    conv3_mfma<<<1024, 256, 0, stream>>>(outu, w3b, A3, B3, out);
    copy_in_k<<<16384, 256, 0, stream>>>(input, out);
}